// Round 1
// baseline (383.041 us; speedup 1.0000x reference)
//
#include <hip/hip_runtime.h>

#define Bsz 8
#define Lx 4096
#define DM 64
#define DI 128
#define NS 16
#define RK 4
#define KC 4
#define NC 32
#define CT 128
#define SS 16
#define TRA 32
#define TRE 16

__device__ __forceinline__ float fsig(float x){ return 1.f/(1.f+__expf(-x)); }

// Kernel A: LN + in_proj + conv + silu + x_proj + dt softplus
__global__ __launch_bounds__(256) void ka_front(
    const float* __restrict__ x, const float* __restrict__ ln_g, const float* __restrict__ ln_b,
    const float* __restrict__ in_w, const float* __restrict__ conv_w, const float* __restrict__ conv_b,
    const float* __restrict__ xp_w, const float* __restrict__ dtp_w, const float* __restrict__ dt_b,
    float* __restrict__ xcg, float* __restrict__ dtg, float* __restrict__ zg,
    float* __restrict__ Bg, float* __restrict__ Cg)
{
  __shared__ float s_xn[TRA+3][DM];
  __shared__ float s_xz[TRA+3][2*DI];
  __shared__ float s_xc[TRA][DI];
  __shared__ float s_dtl[TRA][RK];
  const int tid = threadIdx.x;
  const int ntile = Lx / TRA;
  const int bx = blockIdx.x;
  const int tile = bx % ntile;
  const int i = (bx / ntile) & 1;
  const int b = bx / (2*ntile);
  const int l0 = tile * TRA;
  const int wv = tid >> 6, lane = tid & 63;
  // stage 1: load + layernorm (dir-local rows l0-3 .. l0+TRA-1)
  for (int rr = wv; rr < TRA+3; rr += 4) {
    int l = l0 - 3 + rr;
    float v = 0.f;
    if (l >= 0) {
      int pl = i ? (Lx-1-l) : l;
      v = x[((size_t)b*Lx + pl)*DM + lane];
      float s = v, s2 = v*v;
      #pragma unroll
      for (int off=32; off; off>>=1){ s += __shfl_xor(s,off); s2 += __shfl_xor(s2,off); }
      float mu = s * (1.f/DM);
      float rs = rsqrtf(s2*(1.f/DM) - mu*mu + 1e-5f);
      v = (v-mu)*rs*ln_g[lane] + ln_b[lane];
    }
    s_xn[rr][lane] = v;   // rows with l<0 stay exactly 0 -> in_proj gives 0 (conv zero-pad)
  }
  __syncthreads();
  // stage 2: in_proj — thread owns out-channel c, all 35 rows
  {
    const int c = tid;
    const float4* w4 = (const float4*)(in_w + ((size_t)(i*2*DI) + c)*DM);
    float acc[TRA+3];
    #pragma unroll
    for (int rr=0;rr<TRA+3;++rr) acc[rr]=0.f;
    #pragma unroll
    for (int kb=0;kb<4;++kb){
      float4 w0=w4[kb*4+0], w1=w4[kb*4+1], w2=w4[kb*4+2], w3=w4[kb*4+3];
      #pragma unroll
      for (int rr=0;rr<TRA+3;++rr){
        const float4* xr = (const float4*)(&s_xn[rr][kb*16]);
        float4 x0=xr[0], x1=xr[1], x2=xr[2], x3=xr[3];
        float t0 = fmaf(w0.x,x0.x, fmaf(w0.y,x0.y, fmaf(w0.z,x0.z, w0.w*x0.w)));
        float t1 = fmaf(w1.x,x1.x, fmaf(w1.y,x1.y, fmaf(w1.z,x1.z, w1.w*x1.w)));
        float t2 = fmaf(w2.x,x2.x, fmaf(w2.y,x2.y, fmaf(w2.z,x2.z, w2.w*x2.w)));
        float t3 = fmaf(w3.x,x3.x, fmaf(w3.y,x3.y, fmaf(w3.z,x3.z, w3.w*x3.w)));
        acc[rr] += (t0+t1)+(t2+t3);
      }
    }
    #pragma unroll
    for (int rr=0;rr<TRA+3;++rr) s_xz[rr][c] = acc[rr];
  }
  __syncthreads();
  // stage 3: causal conv + bias + silu; store xc and raw z
  const size_t rbase = ((size_t)(b*2+i)*Lx + l0);
  {
    const float* cw = conv_w + i*DI*KC;
    const float* cb = conv_b + i*DI;
    #pragma unroll
    for (int it=0, e=tid; it < (TRA*DI)/256; ++it, e += 256) {
      int r = e >> 7, d = e & (DI-1);
      float4 w = *(const float4*)(cw + d*KC);
      float acc = cb[d] + w.x*s_xz[r][d] + w.y*s_xz[r+1][d] + w.z*s_xz[r+2][d] + w.w*s_xz[r+3][d];
      float v = acc * fsig(acc);
      s_xc[r][d] = v;
      xcg[(rbase + r)*DI + d] = v;
      zg[(rbase + r)*DI + d] = s_xz[r+3][DI + d];
    }
  }
  __syncthreads();
  // stage 4: x_proj (36 outputs per row, K=128)
  for (int e = tid; e < TRA*36; e += 256) {
    int r = e / 36, j = e - r*36;
    const float4* w4 = (const float4*)(xp_w + ((size_t)(i*36) + j)*DI);
    const float4* xr = (const float4*)(&s_xc[r][0]);
    float acc = 0.f;
    #pragma unroll
    for (int k=0;k<DI/4;++k){
      float4 w = w4[k]; float4 xv = xr[k];
      acc += fmaf(w.x,xv.x, fmaf(w.y,xv.y, fmaf(w.z,xv.z, w.w*xv.w)));
    }
    if (j < RK) s_dtl[r][j] = acc;
    else if (j < RK+NS) Bg[(rbase + r)*NS + (j-RK)] = acc;
    else Cg[(rbase + r)*NS + (j-RK-NS)] = acc;
  }
  __syncthreads();
  // stage 5: dt = softplus(dt_low @ dtp_w^T + bias)
  {
    const float4* dw = (const float4*)(dtp_w + (size_t)i*DI*RK);
    const float* db = dt_b + i*DI;
    #pragma unroll
    for (int it=0, e=tid; it < (TRA*DI)/256; ++it, e += 256) {
      int r = e >> 7, d = e & (DI-1);
      float4 w = dw[d];
      float acc = db[d] + w.x*s_dtl[r][0] + w.y*s_dtl[r][1] + w.z*s_dtl[r][2] + w.w*s_dtl[r][3];
      float sp = (acc > 20.f) ? acc : log1pf(__expf(acc));
      dtg[(rbase + r)*DI + d] = sp;
    }
  }
}

// Kernel B: pass1 — per-chunk local scan (h0=0) + transition product P=exp(A*sum(dt))
__global__ __launch_bounds__(256) void kb_pass1(
    const float* __restrict__ dtg, const float* __restrict__ xcg, const float* __restrict__ Bg,
    const float* __restrict__ A_log,
    float* __restrict__ Pm, float* __restrict__ hend)
{
  __shared__ float s_dt[SS][DI];
  __shared__ float s_x[SS][DI];
  __shared__ float s_B[SS][NS];
  const int tid = threadIdx.x;
  const int bx = blockIdx.x;
  const int c = bx % NC; const int i = (bx/NC)&1; const int b = bx/(2*NC);
  const int d = tid >> 1, n0 = (tid&1)*8;
  float a[8], h[8];
  #pragma unroll
  for (int n=0;n<8;++n){
    a[n] = -__expf(A_log[((size_t)(i*DI)+d)*NS + n0+n]);
    h[n] = 0.f;
  }
  float S = 0.f;
  const size_t rb = ((size_t)(b*2+i)*Lx + (size_t)c*CT);
  for (int s=0; s<CT/SS; ++s){
    __syncthreads();
    #pragma unroll
    for (int it=0, e=tid; it<(SS*DI)/256; ++it, e+=256){
      int t = e >> 7, dd = e & (DI-1);
      size_t g = (rb + s*SS + t)*DI + dd;
      s_dt[t][dd] = dtg[g];
      s_x[t][dd]  = xcg[g];
    }
    {
      int t = tid >> 4, nn = tid & (NS-1);
      s_B[t][nn] = Bg[(rb + s*SS + t)*NS + nn];
    }
    __syncthreads();
    #pragma unroll
    for (int t=0;t<SS;++t){
      float dtt = s_dt[t][d];
      float u = dtt * s_x[t][d];
      S += dtt;
      float4 b0 = *(const float4*)(&s_B[t][n0]);
      float4 b1 = *(const float4*)(&s_B[t][n0+4]);
      float bb[8] = {b0.x,b0.y,b0.z,b0.w,b1.x,b1.y,b1.z,b1.w};
      #pragma unroll
      for (int n=0;n<8;++n){
        float dA = __expf(a[n]*dtt);
        h[n] = fmaf(dA, h[n], u*bb[n]);
      }
    }
  }
  size_t ob = (((size_t)(b*2+i)*NC + c)*DI + d)*NS + n0;
  #pragma unroll
  for (int n=0;n<8;++n){
    Pm[ob+n] = __expf(a[n]*S);
    hend[ob+n] = h[n];
  }
}

// Kernel C: pass2 — propagate chunk boundary states
__global__ __launch_bounds__(256) void kc_pass2(
    const float* __restrict__ Pm, const float* __restrict__ hend, float* __restrict__ h0)
{
  const int tid = threadIdx.x;
  const int bi = blockIdx.x; // b*2+i
  const int d = tid>>1, n0 = (tid&1)*8;
  float h[8];
  #pragma unroll
  for (int n=0;n<8;++n) h[n]=0.f;
  for (int c=0;c<NC;++c){
    size_t ob = (((size_t)bi*NC + c)*DI + d)*NS + n0;
    float p[8], he[8];
    #pragma unroll
    for (int n=0;n<8;++n){ p[n]=Pm[ob+n]; he[n]=hend[ob+n]; }
    #pragma unroll
    for (int n=0;n<8;++n){ h0[ob+n] = h[n]; h[n] = fmaf(p[n], h[n], he[n]); }
  }
}

// Kernel D: pass3 — scan with true h0, y = C.h, fuse D-skip + silu(z) gate; y_g overwrites z
__global__ __launch_bounds__(256) void kd_pass3(
    const float* __restrict__ dtg, const float* __restrict__ xcg, const float* __restrict__ Bg,
    const float* __restrict__ Cg, const float* __restrict__ A_log, const float* __restrict__ Dp,
    const float* __restrict__ h0, float* __restrict__ zyg)
{
  __shared__ float s_dt[SS][DI];
  __shared__ float s_x[SS][DI];
  __shared__ float s_z[SS][DI];
  __shared__ float s_B[SS][NS];
  __shared__ float s_C[SS][NS];
  const int tid = threadIdx.x;
  const int bx = blockIdx.x;
  const int c = bx % NC; const int i = (bx/NC)&1; const int b = bx/(2*NC);
  const int d = tid >> 1, half = tid & 1, n0 = half*8;
  float a[8], h[8];
  size_t hb = (((size_t)(b*2+i)*NC + c)*DI + d)*NS + n0;
  #pragma unroll
  for (int n=0;n<8;++n){
    a[n] = -__expf(A_log[((size_t)(i*DI)+d)*NS + n0+n]);
    h[n] = h0[hb+n];
  }
  const float Dd = Dp[i*DI + d];
  const size_t rb = ((size_t)(b*2+i)*Lx + (size_t)c*CT);
  for (int s=0; s<CT/SS; ++s){
    __syncthreads();
    #pragma unroll
    for (int it=0, e=tid; it<(SS*DI)/256; ++it, e+=256){
      int t = e >> 7, dd = e & (DI-1);
      size_t g = (rb + s*SS + t)*DI + dd;
      s_dt[t][dd] = dtg[g];
      s_x[t][dd]  = xcg[g];
      s_z[t][dd]  = zyg[g];
    }
    {
      int t = tid >> 4, nn = tid & (NS-1);
      s_B[t][nn] = Bg[(rb + s*SS + t)*NS + nn];
      s_C[t][nn] = Cg[(rb + s*SS + t)*NS + nn];
    }
    __syncthreads();
    #pragma unroll
    for (int t=0;t<SS;++t){
      float dtt = s_dt[t][d];
      float xcv = s_x[t][d];
      float u = dtt * xcv;
      float4 b0 = *(const float4*)(&s_B[t][n0]);
      float4 b1 = *(const float4*)(&s_B[t][n0+4]);
      float4 c0 = *(const float4*)(&s_C[t][n0]);
      float4 c1 = *(const float4*)(&s_C[t][n0+4]);
      float bb[8] = {b0.x,b0.y,b0.z,b0.w,b1.x,b1.y,b1.z,b1.w};
      float cc[8] = {c0.x,c0.y,c0.z,c0.w,c1.x,c1.y,c1.z,c1.w};
      float part = 0.f;
      #pragma unroll
      for (int n=0;n<8;++n){
        float dA = __expf(a[n]*dtt);
        h[n] = fmaf(dA, h[n], u*bb[n]);
        part = fmaf(h[n], cc[n], part);
      }
      float y = part + __shfl_xor(part, 1);
      if (half == 0){
        float zz = s_z[t][d];
        zyg[(rb + s*SS + t)*DI + d] = fmaf(xcv, Dd, y) * (zz * fsig(zz));
      }
    }
  }
}

// Kernel E: out-proj, sum both directions (dir1 read flipped)
__global__ __launch_bounds__(256) void ke_out(
    const float* __restrict__ yg, const float* __restrict__ ow, float* __restrict__ out)
{
  __shared__ float s_y0[TRE][DI];
  __shared__ float s_y1[TRE][DI];
  const int tid = threadIdx.x;
  const int bx = blockIdx.x;
  const int ntile = Lx / TRE;
  const int tile = bx % ntile; const int b = bx / ntile;
  const int l0 = tile * TRE;
  #pragma unroll
  for (int it=0, e=tid; it<(TRE*DI)/256; ++it, e+=256){
    int r = e >> 7, dd = e & (DI-1);
    s_y0[r][dd] = yg[((size_t)(b*2+0)*Lx + (size_t)(l0+r))*DI + dd];
    s_y1[r][dd] = yg[((size_t)(b*2+1)*Lx + (size_t)(Lx-1-(l0+r)))*DI + dd];
  }
  __syncthreads();
  const int m = tid & 63, r0 = tid >> 6;
  const float4* w0 = (const float4*)(ow + (size_t)m*DI);
  const float4* w1 = (const float4*)(ow + (size_t)(DM+m)*DI);
  float acc[4] = {0.f,0.f,0.f,0.f};
  #pragma unroll
  for (int k=0;k<DI/4;++k){
    float4 a0 = w0[k], a1 = w1[k];
    #pragma unroll
    for (int j=0;j<4;++j){
      const float4 y0 = *(const float4*)(&s_y0[r0+j*4][k*4]);
      const float4 y1 = *(const float4*)(&s_y1[r0+j*4][k*4]);
      acc[j] += fmaf(a0.x,y0.x, fmaf(a0.y,y0.y, fmaf(a0.z,y0.z, a0.w*y0.w)))
              + fmaf(a1.x,y1.x, fmaf(a1.y,y1.y, fmaf(a1.z,y1.z, a1.w*y1.w)));
    }
  }
  #pragma unroll
  for (int j=0;j<4;++j)
    out[((size_t)b*Lx + (size_t)(l0 + r0 + j*4))*DM + m] = acc[j];
}

extern "C" void kernel_launch(void* const* d_in, const int* in_sizes, int n_in,
                              void* d_out, int out_size, void* d_ws, size_t ws_size,
                              hipStream_t stream)
{
  const float* x      = (const float*)d_in[0];
  const float* ln_g   = (const float*)d_in[1];
  const float* ln_b   = (const float*)d_in[2];
  const float* in_w   = (const float*)d_in[3];
  const float* conv_w = (const float*)d_in[4];
  const float* conv_b = (const float*)d_in[5];
  const float* xp_w   = (const float*)d_in[6];
  const float* dtp_w  = (const float*)d_in[7];
  const float* dt_b   = (const float*)d_in[8];
  const float* A_log  = (const float*)d_in[9];
  const float* Dp     = (const float*)d_in[10];
  const float* ow     = (const float*)d_in[11];
  float* out = (float*)d_out;
  float* ws = (float*)d_ws;
  const size_t NBD = (size_t)Bsz*2*Lx*DI;    // 8,388,608 floats
  const size_t NBN = (size_t)Bsz*2*Lx*NS;    // 1,048,576
  const size_t NCH = (size_t)Bsz*2*NC*DI*NS; // 1,048,576
  float* xcg = ws;
  float* dtg = xcg + NBD;
  float* zyg = dtg + NBD;
  float* Bg  = zyg + NBD;
  float* Cg  = Bg + NBN;
  float* Pm  = Cg + NBN;
  float* he  = Pm + NCH;
  float* h0  = he + NCH;

  ka_front<<<dim3(Bsz*2*(Lx/TRA)), dim3(256), 0, stream>>>(
      x, ln_g, ln_b, in_w, conv_w, conv_b, xp_w, dtp_w, dt_b, xcg, dtg, zyg, Bg, Cg);
  kb_pass1<<<dim3(Bsz*2*NC), dim3(256), 0, stream>>>(dtg, xcg, Bg, A_log, Pm, he);
  kc_pass2<<<dim3(Bsz*2), dim3(256), 0, stream>>>(Pm, he, h0);
  kd_pass3<<<dim3(Bsz*2*NC), dim3(256), 0, stream>>>(dtg, xcg, Bg, Cg, A_log, Dp, h0, zyg);
  ke_out<<<dim3(Bsz*(Lx/TRE)), dim3(256), 0, stream>>>(zyg, ow, out);
}